// Round 10
// baseline (762.206 us; speedup 1.0000x reference)
//
#include <hip/hip_runtime.h>
#include <hip/hip_cooperative_groups.h>

namespace cg = cooperative_groups;

typedef __bf16 bf16;
typedef __bf16 bf16x4 __attribute__((ext_vector_type(4)));
typedef __bf16 bf16x8 __attribute__((ext_vector_type(8)));
typedef float f32x4 __attribute__((ext_vector_type(4)));

#define MFMA16(a, b, c) __builtin_amdgcn_mfma_f32_16x16x32_bf16((a), (b), (c), 0, 0, 0)

// Q pre-scale: 1/sqrt(64) * log2(e), so attention uses exp2 directly.
#define QSCALE 0.1803368808f

__device__ __forceinline__ void async_cp16(const bf16* g, bf16* l) {
    __builtin_amdgcn_global_load_lds((const __attribute__((address_space(1))) void*)g,
                                     (__attribute__((address_space(3))) void*)l, 16, 0, 0);
}

// ---------------- fp32 -> bf16 conversion unit (one 256x8 chunk) ----------
struct CvtArgs { const float* src[7]; bf16* dst[7]; };
__device__ __forceinline__ void cvt_unit(const CvtArgs& a, int bx) {
    int t, off;
    if (bx < 12288) { t = bx >> 12;                off = bx & 4095; }
    else            { t = 3 + ((bx - 12288) >> 9); off = (bx - 12288) & 511; }
    size_t i = (size_t)off * 256 + threadIdx.x;
    const float4* p = (const float4*)(a.src[t] + i * 8);
    float4 x = p[0], y = p[1];
    bf16x8 o;
    o[0] = (bf16)x.x; o[1] = (bf16)x.y; o[2] = (bf16)x.z; o[3] = (bf16)x.w;
    o[4] = (bf16)y.x; o[5] = (bf16)y.y; o[6] = (bf16)y.z; o[7] = (bf16)y.w;
    *(bf16x8*)(a.dst[t] + i * 8) = o;
}

// ---------------- 128x128 GEMM tile (r5-proven: 0 conflicts) --------------
// BK=64, single-buffered, 2-barrier. Row = 128B = 8 chunks; both-sides
// swizzle c^(r&7). Structural note (r1/r3/r4/r6/r8): every pipelining /
// 256-tile / phase-split variant measured WORSE. Do not revisit.
// mode 0: Q -> bf16 [B,H,S,D], (acc+bias)*QSCALE; mode 1: K -> [B,H,S,D]
// mode 2: V^T -> [B,H,D,S'] token-permuted; mode 3: fp32 [M,1024]
__device__ __forceinline__ void gemm_tile(
    const bf16* __restrict__ A, const bf16* __restrict__ W,
    const float* __restrict__ bias, void* __restrict__ Cout,
    int mode, int m0, int n0, bf16* As, bf16* Bs)
{
    const int K = 1024;
    const int tid = threadIdx.x;
    const int lane = tid & 63, wave = tid >> 6;
    const int l15 = lane & 15, quad = lane >> 4, l7 = l15 & 7;
    const int wm = wave >> 1, wn = wave & 1;

    f32x4 acc[4][4] = {};

    const int rb = tid >> 3;
    const int cg8 = ((tid & 7) ^ (rb & 7)) * 8;
    const bf16* Ag = A + (size_t)(m0 + rb) * K + cg8;
    const bf16* Wg = W + (size_t)(n0 + rb) * K + cg8;
    bf16* Al = As + tid * 8;
    bf16* Bl = Bs + tid * 8;

    for (int k0 = 0; k0 < K; k0 += 64) {
        __syncthreads();
#pragma unroll
        for (int j = 0; j < 4; ++j) {
            async_cp16(Ag + k0 + (size_t)(j * 32) * K, Al + j * 2048);
            async_cp16(Wg + k0 + (size_t)(j * 32) * K, Bl + j * 2048);
        }
        __syncthreads();

#pragma unroll
        for (int ks = 0; ks < 2; ++ks) {
            bf16x8 af[4], bfr[4];
#pragma unroll
            for (int t = 0; t < 4; ++t) {
                const int sw = ((ks * 4 + quad) ^ l7) * 8;
                af[t]  = *(const bf16x8*)(As + (wm * 64 + t * 16 + l15) * 64 + sw);
                bfr[t] = *(const bf16x8*)(Bs + (wn * 64 + t * 16 + l15) * 64 + sw);
            }
#pragma unroll
            for (int mt = 0; mt < 4; ++mt)
#pragma unroll
                for (int nt = 0; nt < 4; ++nt)
                    acc[mt][nt] = MFMA16(af[mt], bfr[nt], acc[mt][nt]);
        }
    }

#pragma unroll
    for (int mt = 0; mt < 4; ++mt) {
#pragma unroll
        for (int nt = 0; nt < 4; ++nt) {
            int col = n0 + wn * 64 + nt * 16 + l15;
            float bcol = (mode == 2) ? 0.0f : bias[col];
#pragma unroll
            for (int r = 0; r < 4; ++r) {
                int row = m0 + wm * 64 + mt * 16 + quad * 4 + r;
                float val = acc[mt][nt][r];
                if (mode == 2) {
                    val += bias[row];
                    int bb = col >> 11, s = col & 2047;
                    int u = s & 31;
                    int sp = (s & ~31) | (((u >> 2) & 3) * 8 + (u >> 4) * 4 + (u & 3));
                    ((bf16*)Cout)[((size_t)(bb * 1024 + row) << 11) + sp] = (bf16)val;
                } else if (mode == 3) {
                    ((float*)Cout)[(size_t)row * 1024 + col] = val + bcol;
                } else {
                    val += bcol;
                    if (mode == 0) val *= QSCALE;
                    int bb = row >> 11, s = row & 2047, hh = col >> 6, d = col & 63;
                    ((bf16*)Cout)[(((size_t)(bb * 16 + hh) * 2048 + s) << 6) + d] = (bf16)val;
                }
            }
        }
    }
    __syncthreads();   // safe reuse of As/Bs by the caller's next tile
}

// ---------------- flash attention tile (r7-proven form) -------------------
// 32 q-rows/wave, 4 waves = 128 q-rows/block; K/V staged via LDS (r9 proved
// direct-from-L2 is 2.7x worse: latency chains + no ds-decoupling).
// S^T = K.Q^T; V^T token-permuted to match PV B-operand layout.
__device__ __forceinline__ void attn_tile(
    const bf16* __restrict__ Qh, const bf16* __restrict__ Kh,
    const bf16* __restrict__ Vtg, bf16* __restrict__ AO,
    int bid, bf16* Kl, bf16* Vl)
{
    const int tid = threadIdx.x;
    const int lane = tid & 63, wave = tid >> 6;
    const int l15 = lane & 15, quad = lane >> 4, l7 = l15 & 7;
    const int g = bid & 63, qi = bid >> 6;
    const int h = g & 15, b = g >> 4;
    const size_t base = (size_t)(b * 16 + h) << 17;   // * 2048 * 64
    const int q0 = qi * 128 + wave * 32;

    bf16x8 qf[2][2];
#pragma unroll
    for (int qt = 0; qt < 2; ++qt)
#pragma unroll
        for (int ks = 0; ks < 2; ++ks)
            qf[qt][ks] = *(const bf16x8*)(Qh + base + (q0 + qt * 16 + l15) * 64 + ks * 32 + quad * 8);

    f32x4 o[4][2] = {};   // O^T tiles: [dt][qt], lane l15=q, rows d=quad*4+r
    float ls[2] = {};     // per-q partial row sums (q = l15)

    const int sr = tid >> 3;
    const int sc0 = ((tid & 7) ^ (sr & 7)) * 8;
    const int sr2 = sr + 32;

    for (int kt = 0; kt < 2048; kt += 64) {
        __syncthreads();
        async_cp16(Kh + base + (size_t)(kt + sr) * 64 + sc0, Kl + tid * 8);
        async_cp16(Kh + base + (size_t)(kt + sr2) * 64 + sc0, Kl + (tid + 256) * 8);
        async_cp16(Vtg + base + (size_t)sr * 2048 + kt + sc0, Vl + tid * 8);
        async_cp16(Vtg + base + (size_t)sr2 * 2048 + kt + sc0, Vl + (tid + 256) * 8);
        __syncthreads();

        bf16x8 kb[2][4];
#pragma unroll
        for (int ks = 0; ks < 2; ++ks)
#pragma unroll
            for (int ktile = 0; ktile < 4; ++ktile)
                kb[ks][ktile] = *(const bf16x8*)(Kl + (ktile * 16 + l15) * 64 + (((ks * 4 + quad) ^ l7) * 8));

        bf16x8 pf[2][2];   // [qt][kc]: keys kc*32 + quad*8 + {0..7} (V' ordering)
#pragma unroll
        for (int qt = 0; qt < 2; ++qt) {
            f32x4 sc[4] = {};
#pragma unroll
            for (int ks = 0; ks < 2; ++ks)
#pragma unroll
                for (int ktile = 0; ktile < 4; ++ktile)
                    sc[ktile] = MFMA16(kb[ks][ktile], qf[qt][ks], sc[ktile]);
            float sum = 0.0f;
#pragma unroll
            for (int kc = 0; kc < 2; ++kc) {
                bf16x8 pk;
#pragma unroll
                for (int t = 0; t < 2; ++t)
#pragma unroll
                    for (int r = 0; r < 4; ++r) {
                        float p = __builtin_amdgcn_exp2f(sc[kc * 2 + t][r]);
                        sum += p;
                        pk[t * 4 + r] = (bf16)p;
                    }
                pf[qt][kc] = pk;
            }
            ls[qt] += sum;
        }

        bf16x8 va[4][2];
#pragma unroll
        for (int dt = 0; dt < 4; ++dt)
#pragma unroll
            for (int kc = 0; kc < 2; ++kc)
                va[dt][kc] = *(const bf16x8*)(Vl + (dt * 16 + l15) * 64 + (((kc * 4 + quad) ^ l7) * 8));

#pragma unroll
        for (int dt = 0; dt < 4; ++dt)
#pragma unroll
            for (int qt = 0; qt < 2; ++qt)
#pragma unroll
                for (int kc = 0; kc < 2; ++kc)
                    o[dt][qt] = MFMA16(va[dt][kc], pf[qt][kc], o[dt][qt]);
    }

#pragma unroll
    for (int qt = 0; qt < 2; ++qt) {
        float l = ls[qt];
        l += __shfl_xor(l, 16, 64);
        l += __shfl_xor(l, 32, 64);
        float inv = 1.0f / l;
        size_t rb = ((size_t)(b * 2048 + q0 + qt * 16 + l15)) * 1024 + h * 64;
#pragma unroll
        for (int dt = 0; dt < 4; ++dt) {
            bf16x4 ov = {(bf16)(o[dt][qt][0] * inv), (bf16)(o[dt][qt][1] * inv),
                         (bf16)(o[dt][qt][2] * inv), (bf16)(o[dt][qt][3] * inv)};
            *(bf16x4*)(AO + rb + dt * 16 + quad * 4) = ov;
        }
    }
    __syncthreads();
}

struct QkvArgs {
    const bf16* A[3];
    const bf16* W[3];
    const float* bias[3];
    bf16* out[3];
};

struct FusedArgs {
    CvtArgs cvt;
    QkvArgs qkv;
    const bf16* Qh; const bf16* Kh; const bf16* Vt; bf16* AO;
    const bf16* Wob; const float* bo; float* out;
};

// ---------------- fused cooperative pipeline ------------------------------
// 4 dispatches -> 1: the measured inter-dispatch overhead (~95us repro'd in
// r7/r9 tallies) exceeded any remaining kernel-level inefficiency. Grid 1024
// x 256 = exactly 4 blocks/CU (LDS 32KB union -> 128KB/CU; VGPR capped 128
// via launch_bounds). Stage bodies are byte-identical to r5/r7-proven forms.
__global__ __launch_bounds__(256, 4) void fused_mha(FusedArgs a) {
    __shared__ __align__(16) bf16 smem[16384];   // 32KB: gemm As|Bs, attn Kl|Vl
    cg::grid_group grid = cg::this_grid();

    // stage 0: cvt — 14336 units, 14 per block (uniform)
    for (int u = blockIdx.x; u < 14336; u += 1024) cvt_unit(a.cvt, u);
    grid.sync();

    // stage 1: qkv — 1536 tiles (z = v>>9), XCD/L2 remap (r5: FETCH -2x)
    for (int v = blockIdx.x; v < 1536; v += 1024) {
        int z = v >> 9, bid = v & 511;
        int lo = bid & 7, mid = (bid >> 3) & 7, hi = bid >> 6;
        int m0, n0;
        if (z < 2) { m0 = (lo + hi * 8) * 128; n0 = mid * 128; }
        else       { m0 = mid * 128;           n0 = (lo + hi * 8) * 128; }
        gemm_tile(a.qkv.A[z], a.qkv.W[z], a.qkv.bias[z], a.qkv.out[z], z,
                  m0, n0, smem, smem + 8192);
    }
    grid.sync();

    // stage 2: attn — 1024 blocks, 1:1
    attn_tile(a.Qh, a.Kh, a.Vt, a.AO, blockIdx.x, smem, smem + 4096);
    grid.sync();

    // stage 3: oproj — 512 tiles
    if (blockIdx.x < 512) {
        int v = blockIdx.x;
        gemm_tile(a.AO, a.Wob, a.bo, a.out, 3, (v & 63) * 128, (v >> 6) * 128,
                  smem, smem + 8192);
    }
}

// ---------------- standalone fallback kernels (r7 config) -----------------
__global__ void cvt_all(CvtArgs a) { cvt_unit(a, blockIdx.x); }

__global__ __launch_bounds__(256) void qkv_gemm(QkvArgs t) {
    __shared__ __align__(16) bf16 smem[16384];
    int z = blockIdx.y;
    int bid = blockIdx.x;
    int lo = bid & 7, mid = (bid >> 3) & 7, hi = bid >> 6;
    int m0, n0;
    if (z < 2) { m0 = (lo + hi * 8) * 128; n0 = mid * 128; }
    else       { m0 = mid * 128;           n0 = (lo + hi * 8) * 128; }
    gemm_tile(t.A[z], t.W[z], t.bias[z], t.out[z], z, m0, n0, smem, smem + 8192);
}

__global__ __launch_bounds__(256) void oproj_gemm(
    const bf16* __restrict__ A, const bf16* __restrict__ W,
    const float* __restrict__ bias, float* __restrict__ Cout) {
    __shared__ __align__(16) bf16 smem[16384];
    gemm_tile(A, W, bias, Cout, 3, blockIdx.x * 128, blockIdx.y * 128,
              smem, smem + 8192);
}

__global__ __launch_bounds__(256, 4) void attn_kernel(
    const bf16* __restrict__ Qh, const bf16* __restrict__ Kh,
    const bf16* __restrict__ Vtg, bf16* __restrict__ AO) {
    __shared__ __align__(16) bf16 smem[8192];
    attn_tile(Qh, Kh, Vtg, AO, blockIdx.x, smem, smem + 4096);
}

// ---------------- host ----------------
extern "C" void kernel_launch(void* const* d_in, const int* in_sizes, int n_in,
                              void* d_out, int out_size, void* d_ws, size_t ws_size,
                              hipStream_t stream) {
    const float* q  = (const float*)d_in[0];
    const float* k  = (const float*)d_in[1];
    const float* v  = (const float*)d_in[2];
    const float* Wq = (const float*)d_in[3];
    const float* bq = (const float*)d_in[4];
    const float* Wk = (const float*)d_in[5];
    const float* bk = (const float*)d_in[6];
    const float* Wv = (const float*)d_in[7];
    const float* bv = (const float*)d_in[8];
    const float* Wo = (const float*)d_in[9];
    const float* bo = (const float*)d_in[10];
    float* out = (float*)d_out;

    const size_t NX = (size_t)8192 * 1024;
    const size_t NW = (size_t)1024 * 1024;
    bf16* ws  = (bf16*)d_ws;
    bf16* Xq  = ws;            // reused as AO after projections
    bf16* Xk  = Xq + NX;
    bf16* Xv  = Xk + NX;
    bf16* Wqb = Xv + NX;
    bf16* Wkb = Wqb + NW;
    bf16* Wvb = Wkb + NW;
    bf16* Wob = Wvb + NW;
    bf16* Qh  = Wob + NW;      // [B,H,S,D], pre-scaled by QSCALE
    bf16* Kh  = Qh + NX;       // [B,H,S,D]
    bf16* Vt  = Kh + NX;       // [B,H,D,S'] (tokens permuted within 32-groups)
    bf16* AO  = Xq;

    FusedArgs fa;
    fa.cvt.src[0] = q;  fa.cvt.dst[0] = Xq;
    fa.cvt.src[1] = k;  fa.cvt.dst[1] = Xk;
    fa.cvt.src[2] = v;  fa.cvt.dst[2] = Xv;
    fa.cvt.src[3] = Wq; fa.cvt.dst[3] = Wqb;
    fa.cvt.src[4] = Wk; fa.cvt.dst[4] = Wkb;
    fa.cvt.src[5] = Wv; fa.cvt.dst[5] = Wvb;
    fa.cvt.src[6] = Wo; fa.cvt.dst[6] = Wob;
    fa.qkv.A[0] = Xq;  fa.qkv.W[0] = Wqb; fa.qkv.bias[0] = bq; fa.qkv.out[0] = Qh;
    fa.qkv.A[1] = Xk;  fa.qkv.W[1] = Wkb; fa.qkv.bias[1] = bk; fa.qkv.out[1] = Kh;
    fa.qkv.A[2] = Wvb; fa.qkv.W[2] = Xv;  fa.qkv.bias[2] = bv; fa.qkv.out[2] = Vt;
    fa.Qh = Qh; fa.Kh = Kh; fa.Vt = Vt; fa.AO = AO;
    fa.Wob = Wob; fa.bo = bo; fa.out = out;

    void* kargs[] = {(void*)&fa};
    hipError_t err = hipLaunchCooperativeKernel((const void*)fused_mha,
                                                dim3(1024), dim3(256),
                                                kargs, 0, stream);
    if (err != hipSuccess) {
        // fallback: proven r7 4-launch path
        cvt_all<<<14336, 256, 0, stream>>>(fa.cvt);
        qkv_gemm<<<dim3(512, 3), dim3(256, 1, 1), 0, stream>>>(fa.qkv);
        attn_kernel<<<1024, 256, 0, stream>>>(Qh, Kh, Vt, AO);
        oproj_gemm<<<dim3(64, 8), dim3(256, 1, 1), 0, stream>>>(AO, Wob, bo, out);
    }
}